// Round 1
// baseline (17069.380 us; speedup 1.0000x reference)
//
#include <hip/hip_runtime.h>
#include <math.h>

// MLA forward: B=2, S=2048, D=2048, H=16, KV_RANK=512, NOPE=128, ROPE=64
// QK_HD=192, V_HD=128. All inputs/outputs float32.

#define B_ 2
#define S_ 2048
#define D_ 2048
#define H_ 16
#define RANK_ 512
#define NOPE_ 128
#define ROPE_ 64
#define QKHD_ 192
#define VHD_ 128
#define SCALE_ 0.07216878364870323f   // 192^-0.5
#define EPS_ 1.1920929e-07f

// ---------------------------------------------------------------------------
// Generic tiled f32 GEMM: C[m,n] = sum_k A[m,k] * B(n,k or k,n) + bias[n]
// Tile 64x64, BK=16, 256 threads, 4x4 accum per thread. All dims % 64 == 0,
// K % 16 == 0. Batched via blockIdx.z with element strides.
// ---------------------------------------------------------------------------
template<bool B_IS_NT>
__global__ __launch_bounds__(256) void gemm_kernel(
    const float* __restrict__ A, int lda, long long aStride,
    const float* __restrict__ B, int ldb, long long bStride,
    const float* __restrict__ bias,
    float* __restrict__ C, int ldc, long long cStride,
    int K)
{
    __shared__ float As[16][68];
    __shared__ float Bs[16][68];

    const int bz = blockIdx.z;
    A += (long long)bz * aStride;
    B += (long long)bz * bStride;
    C += (long long)bz * cStride;

    const int m0 = blockIdx.y * 64;
    const int n0 = blockIdx.x * 64;
    const int tid = threadIdx.x;
    const int tx = tid & 15;        // n sub-tile
    const int ty = tid >> 4;        // m sub-tile

    const int lr = tid >> 2;        // 0..63 (row within tile)
    const int lk = (tid & 3) * 4;   // 0..12 (k within BK)

    float acc[4][4];
#pragma unroll
    for (int i = 0; i < 4; ++i)
#pragma unroll
        for (int j = 0; j < 4; ++j) acc[i][j] = 0.0f;

    for (int k0 = 0; k0 < K; k0 += 16) {
        // stage A tile (transpose to As[k][m])
        float4 a4 = *(const float4*)&A[(long long)(m0 + lr) * lda + k0 + lk];
        As[lk + 0][lr] = a4.x;
        As[lk + 1][lr] = a4.y;
        As[lk + 2][lr] = a4.z;
        As[lk + 3][lr] = a4.w;

        if (B_IS_NT) {
            // B is (N,K): row n, cols k
            float4 b4 = *(const float4*)&B[(long long)(n0 + lr) * ldb + k0 + lk];
            Bs[lk + 0][lr] = b4.x;
            Bs[lk + 1][lr] = b4.y;
            Bs[lk + 2][lr] = b4.z;
            Bs[lk + 3][lr] = b4.w;
        } else {
            // B is (K,N): row k, cols n
            const int bk = tid >> 4;         // 0..15
            const int bn = (tid & 15) * 4;   // 0..60
            float4 b4 = *(const float4*)&B[(long long)(k0 + bk) * ldb + n0 + bn];
            *(float4*)&Bs[bk][bn] = b4;
        }
        __syncthreads();

#pragma unroll
        for (int k = 0; k < 16; ++k) {
            float4 av = *(const float4*)&As[k][ty * 4];
            float4 bv = *(const float4*)&Bs[k][tx * 4];
            float am[4] = {av.x, av.y, av.z, av.w};
            float bm[4] = {bv.x, bv.y, bv.z, bv.w};
#pragma unroll
            for (int i = 0; i < 4; ++i)
#pragma unroll
                for (int j = 0; j < 4; ++j) acc[i][j] += am[i] * bm[j];
        }
        __syncthreads();
    }

#pragma unroll
    for (int i = 0; i < 4; ++i) {
        const int m = m0 + ty * 4 + i;
        float4 cv;
        cv.x = acc[i][0]; cv.y = acc[i][1]; cv.z = acc[i][2]; cv.w = acc[i][3];
        if (bias) {
            const int n = n0 + tx * 4;
            cv.x += bias[n + 0]; cv.y += bias[n + 1];
            cv.z += bias[n + 2]; cv.w += bias[n + 3];
        }
        *(float4*)&C[(long long)m * ldc + n0 + tx * 4] = cv;
    }
}

// ---------------------------------------------------------------------------
// RoPE on q_raw[..., 128:192]. One thread per (b,s,h,pair). 2,097,152 threads.
// ---------------------------------------------------------------------------
__global__ __launch_bounds__(256) void rope_q_kernel(
    float* __restrict__ q, const float* __restrict__ freqs)
{
    const int idx = blockIdx.x * 256 + threadIdx.x;
    const int i = idx & 31;
    const int h = (idx >> 5) & 15;
    const int s = (idx >> 9) & 2047;
    const int b = idx >> 20;
    const float f = freqs[s * 32 + i];
    float cs, sn;
    __sincosf(f, &sn, &cs);
    const long long base =
        (((long long)(b * S_ + s) * H_ + h) * QKHD_) + NOPE_ + 2 * i;
    const float a = q[base];
    const float bb = q[base + 1];
    q[base]     = a * cs - bb * sn;
    q[base + 1] = a * sn + bb * cs;
}

// ---------------------------------------------------------------------------
// kv post-process: rmsnorm of kv_raw[:,0:512] -> kv_proj; rope of
// kv_raw[:,512:576] -> k_pe. One wave per (b,s).
// ---------------------------------------------------------------------------
__global__ __launch_bounds__(64) void kv_post_kernel(
    const float* __restrict__ kv_raw, const float* __restrict__ w,
    const float* __restrict__ freqs, float* __restrict__ kv_proj,
    float* __restrict__ k_pe)
{
    const int bs = blockIdx.x;          // 0..4095
    const int lane = threadIdx.x;       // 0..63
    const float* src = kv_raw + (long long)bs * 576;

    const int c = 4 * lane;
    float4 v0 = *(const float4*)&src[c];
    float4 v1 = *(const float4*)&src[256 + c];
    float ss = v0.x * v0.x + v0.y * v0.y + v0.z * v0.z + v0.w * v0.w +
               v1.x * v1.x + v1.y * v1.y + v1.z * v1.z + v1.w * v1.w;
#pragma unroll
    for (int o = 32; o; o >>= 1) ss += __shfl_xor(ss, o, 64);
    const float rs = rsqrtf(ss * (1.0f / 512.0f) + EPS_);

    float4 w0 = *(const float4*)&w[c];
    float4 w1 = *(const float4*)&w[256 + c];
    float* dst = kv_proj + (long long)bs * 512;
    float4 o0, o1;
    o0.x = v0.x * rs * w0.x; o0.y = v0.y * rs * w0.y;
    o0.z = v0.z * rs * w0.z; o0.w = v0.w * rs * w0.w;
    o1.x = v1.x * rs * w1.x; o1.y = v1.y * rs * w1.y;
    o1.z = v1.z * rs * w1.z; o1.w = v1.w * rs * w1.w;
    *(float4*)&dst[c] = o0;
    *(float4*)&dst[256 + c] = o1;

    if (lane < 32) {
        const int s = bs & 2047;
        const float f = freqs[s * 32 + lane];
        float cs, sn;
        __sincosf(f, &sn, &cs);
        const float a = src[512 + 2 * lane];
        const float b2 = src[512 + 2 * lane + 1];
        k_pe[(long long)bs * 64 + 2 * lane]     = a * cs - b2 * sn;
        k_pe[(long long)bs * 64 + 2 * lane + 1] = a * sn + b2 * cs;
    }
}

// ---------------------------------------------------------------------------
// Flash attention in latent space, causal. One block = 4 waves = 16 query
// rows of one (b,h). Lane owns latent dims {4l..4l+3, 256+4l..4l+3} and rope
// dim l, so the KV registers loaded once per t serve both the score dot and
// the O update (V == kv latent in MLA). Online softmax. Output written in
// place over q_lat.
// ---------------------------------------------------------------------------
__global__ __launch_bounds__(256) void attn_kernel(
    const float* __restrict__ q_lat,   // (B,S,H,512)
    const float* __restrict__ q_raw,   // (B,S,H,192), rope at +128
    const float* __restrict__ kv,      // (B,S,512)
    const float* __restrict__ kpe,     // (B,S,64)
    float* __restrict__ o_lat)         // == q_lat (in-place)
{
    __shared__ float kvs[16 * 576];

    const int b = blockIdx.z;
    const int h = blockIdx.y;
    const int rBase = blockIdx.x * 16;
    const int tid = threadIdx.x;
    const int wid = tid >> 6;
    const int lane = tid & 63;
    const int row0 = rBase + wid * 4;
    const int cl = 4 * lane;

    float4 q0[4], q1[4];
    float qr[4];
#pragma unroll
    for (int r = 0; r < 4; ++r) {
        const long long qb = (long long)(b * S_ + row0 + r) * H_ + h;
        float4 t0v = *(const float4*)&q_lat[qb * 512 + cl];
        float4 t1v = *(const float4*)&q_lat[qb * 512 + 256 + cl];
        q0[r].x = t0v.x * SCALE_; q0[r].y = t0v.y * SCALE_;
        q0[r].z = t0v.z * SCALE_; q0[r].w = t0v.w * SCALE_;
        q1[r].x = t1v.x * SCALE_; q1[r].y = t1v.y * SCALE_;
        q1[r].z = t1v.z * SCALE_; q1[r].w = t1v.w * SCALE_;
        qr[r] = q_raw[qb * QKHD_ + NOPE_ + lane] * SCALE_;
    }

    float m[4], l[4];
    float4 O0[4], O1[4];
#pragma unroll
    for (int r = 0; r < 4; ++r) {
        m[r] = -3.0e38f;
        l[r] = 0.0f;
        O0[r] = make_float4(0.f, 0.f, 0.f, 0.f);
        O1[r] = make_float4(0.f, 0.f, 0.f, 0.f);
    }

    const int tMax = rBase + 15;  // inclusive
    for (int t0 = 0; t0 <= tMax; t0 += 16) {
        // stage 16 KV rows (512 latent + 64 rope = 576 f) into LDS
#pragma unroll
        for (int j = 0; j < 9; ++j) {
            const int v = tid + j * 256;        // float4 index, 0..2303
            const int t = v / 144;
            const int c4 = v - t * 144;
            float4 val;
            if (c4 < 128)
                val = *(const float4*)&kv[(long long)(b * S_ + t0 + t) * 512 + c4 * 4];
            else
                val = *(const float4*)&kpe[(long long)(b * S_ + t0 + t) * 64 + (c4 - 128) * 4];
            *(float4*)&kvs[t * 576 + c4 * 4] = val;
        }
        __syncthreads();

        for (int tt = 0; tt < 16; ++tt) {
            const int t = t0 + tt;
            if (t > row0 + 3) break;   // wave-uniform causal skip
            const float4 k0 = *(const float4*)&kvs[tt * 576 + cl];
            const float4 k1 = *(const float4*)&kvs[tt * 576 + 256 + cl];
            const float kr = kvs[tt * 576 + 512 + lane];
#pragma unroll
            for (int r = 0; r < 4; ++r) {
                if (t > row0 + r) continue;
                float p = q0[r].x * k0.x + q0[r].y * k0.y +
                          q0[r].z * k0.z + q0[r].w * k0.w +
                          q1[r].x * k1.x + q1[r].y * k1.y +
                          q1[r].z * k1.z + q1[r].w * k1.w +
                          qr[r] * kr;
#pragma unroll
                for (int o = 32; o; o >>= 1) p += __shfl_xor(p, o, 64);
                const float mn = fmaxf(m[r], p);
                const float alpha = __expf(m[r] - mn);
                const float pe = __expf(p - mn);
                m[r] = mn;
                l[r] = l[r] * alpha + pe;
                O0[r].x = O0[r].x * alpha + pe * k0.x;
                O0[r].y = O0[r].y * alpha + pe * k0.y;
                O0[r].z = O0[r].z * alpha + pe * k0.z;
                O0[r].w = O0[r].w * alpha + pe * k0.w;
                O1[r].x = O1[r].x * alpha + pe * k1.x;
                O1[r].y = O1[r].y * alpha + pe * k1.y;
                O1[r].z = O1[r].z * alpha + pe * k1.z;
                O1[r].w = O1[r].w * alpha + pe * k1.w;
            }
        }
        __syncthreads();
    }

#pragma unroll
    for (int r = 0; r < 4; ++r) {
        const long long qb = (long long)(b * S_ + row0 + r) * H_ + h;
        const float inv = 1.0f / l[r];
        float4 a, c;
        a.x = O0[r].x * inv; a.y = O0[r].y * inv;
        a.z = O0[r].z * inv; a.w = O0[r].w * inv;
        c.x = O1[r].x * inv; c.y = O1[r].y * inv;
        c.z = O1[r].z * inv; c.w = O1[r].w * inv;
        *(float4*)&o_lat[qb * 512 + cl] = a;
        *(float4*)&o_lat[qb * 512 + 256 + cl] = c;
    }
}

// ---------------------------------------------------------------------------
extern "C" void kernel_launch(void* const* d_in, const int* in_sizes, int n_in,
                              void* d_out, int out_size, void* d_ws, size_t ws_size,
                              hipStream_t stream)
{
    const float* x         = (const float*)d_in[0];
    const float* freqs     = (const float*)d_in[1];
    // d_in[2] = mask (unused: causal handled analytically)
    const float* wq_w      = (const float*)d_in[3];
    const float* wq_b      = (const float*)d_in[4];
    const float* wkv_a_w   = (const float*)d_in[5];
    const float* wkv_a_b   = (const float*)d_in[6];
    const float* kv_norm_w = (const float*)d_in[7];
    const float* wkv_b_w   = (const float*)d_in[8];
    const float* wo_w      = (const float*)d_in[9];
    const float* wo_b      = (const float*)d_in[10];
    float* out = (float*)d_out;

    float* ws = (float*)d_ws;
    float* q_raw   = ws;                      // B*S*H*192 = 12,582,912
    float* kv_raw  = q_raw + 12582912LL;      // B*S*576   =  2,359,296
    float* kv_proj = kv_raw + 2359296LL;      // B*S*512   =  2,097,152
    float* k_pe    = kv_proj + 2097152LL;     // B*S*64    =    262,144
    float* q_lat   = k_pe + 262144LL;         // B*S*H*512 = 33,554,432
    float* out_v   = q_raw;                   // reuse (q_raw dead after attn)
    // total: 50,855,936 floats = 203.4 MB of d_ws

    dim3 blk(256);

    // 1) q_raw = x @ wq_w^T + wq_b   (M=4096, N=3072, K=2048)
    gemm_kernel<true><<<dim3(48, 64, 1), blk, 0, stream>>>(
        x, 2048, 0LL, wq_w, 2048, 0LL, wq_b, q_raw, 3072, 0LL, 2048);

    // 2) kv_raw = x @ wkv_a_w^T + wkv_a_b   (N=576)
    gemm_kernel<true><<<dim3(9, 64, 1), blk, 0, stream>>>(
        x, 2048, 0LL, wkv_a_w, 2048, 0LL, wkv_a_b, kv_raw, 576, 0LL, 2048);

    // 3) RoPE on q_pe (in place)
    rope_q_kernel<<<dim3(8192), blk, 0, stream>>>(q_raw, freqs);

    // 4) rmsnorm kv -> kv_proj; rope k_pe
    kv_post_kernel<<<dim3(4096), dim3(64), 0, stream>>>(
        kv_raw, kv_norm_w, freqs, kv_proj, k_pe);

    // 5) q_lat[b,s,h,:] = q_nope[b,s,h,:] @ wkv_b[h,:128,:]  (NN, batched x16)
    gemm_kernel<false><<<dim3(8, 64, 16), blk, 0, stream>>>(
        q_raw, 3072, 192LL, wkv_b_w, 512, 131072LL, nullptr,
        q_lat, 8192, 512LL, 128);

    // 6) causal flash attention in latent space (in place over q_lat)
    attn_kernel<<<dim3(128, 16, 2), blk, 0, stream>>>(
        q_lat, q_raw, kv_proj, k_pe, q_lat);

    // 7) out_v[b,s,h,:] = attn[b,s,h,:] @ wkv_b[h,128:,:]^T  (NT, batched x16)
    gemm_kernel<true><<<dim3(2, 64, 16), blk, 0, stream>>>(
        q_lat, 8192, 512LL, wkv_b_w + 65536, 512, 131072LL, nullptr,
        out_v, 2048, 128LL, 512);

    // 8) out = out_v @ wo_w^T + wo_b   (M=4096, N=2048, K=2048)
    gemm_kernel<true><<<dim3(32, 64, 1), blk, 0, stream>>>(
        out_v, 2048, 0LL, wo_w, 2048, 0LL, wo_b, out, 2048, 0LL, 2048);
}

// Round 2
// 3259.089 us; speedup vs baseline: 5.2375x; 5.2375x over previous
//
#include <hip/hip_runtime.h>
#include <hip/hip_bf16.h>
#include <math.h>

// MLA forward: B=2, S=2048, D=2048, H=16, KV_RANK=512, NOPE=128, ROPE=64
#define B_ 2
#define S_ 2048
#define D_ 2048
#define H_ 16
#define RANK_ 512
#define NOPE_ 128
#define ROPE_ 64
#define QKHD_ 192
#define VHD_ 128
#define SCALE_ 0.07216878364870323f   // 192^-0.5
#define EPS_ 1.1920929e-07f

typedef __attribute__((ext_vector_type(8))) short bf16x8;
typedef __attribute__((ext_vector_type(4))) float f32x4;

__device__ __forceinline__ uint bfbits(float x) {   // f32 -> bf16 bits, RNE
    uint u = __float_as_uint(x);
    return (u + 0x7fffu + ((u >> 16) & 1u)) >> 16;
}
__device__ __forceinline__ uint pack2bf(float a, float b) {
    return bfbits(a) | (bfbits(b) << 16);
}

// ---------------------------------------------------------------------------
// Tiled f32 GEMM: C[m,n] = sum_k A[m,k]*B(.) + bias[n].  64x64 tile, BK=16,
// 256 thr, 4x4 acc.  A_BF16: A is bf16.  OUT_BF16: C bf16 with outScale.
// ---------------------------------------------------------------------------
template<bool B_IS_NT, bool A_BF16, bool OUT_BF16>
__global__ __launch_bounds__(256) void gemm_kernel(
    const void* __restrict__ Av, int lda, long long aStride,
    const float* __restrict__ B, int ldb, long long bStride,
    const float* __restrict__ bias, float outScale,
    void* __restrict__ Cv, int ldc, long long cStride,
    int K)
{
    __shared__ float As[16][68];
    __shared__ float Bs[16][68];

    const int bz = blockIdx.z;
    B += (long long)bz * bStride;

    const int m0 = blockIdx.y * 64;
    const int n0 = blockIdx.x * 64;
    const int tid = threadIdx.x;
    const int tx = tid & 15;
    const int ty = tid >> 4;
    const int lr = tid >> 2;
    const int lk = (tid & 3) * 4;

    float acc[4][4];
#pragma unroll
    for (int i = 0; i < 4; ++i)
#pragma unroll
        for (int j = 0; j < 4; ++j) acc[i][j] = 0.0f;

    for (int k0 = 0; k0 < K; k0 += 16) {
        if (A_BF16) {
            const __hip_bfloat16* Ab = (const __hip_bfloat16*)Av + (long long)bz * aStride;
            uint2 a2 = *(const uint2*)&Ab[(long long)(m0 + lr) * lda + k0 + lk];
            As[lk + 0][lr] = __uint_as_float(a2.x << 16);
            As[lk + 1][lr] = __uint_as_float(a2.x & 0xffff0000u);
            As[lk + 2][lr] = __uint_as_float(a2.y << 16);
            As[lk + 3][lr] = __uint_as_float(a2.y & 0xffff0000u);
        } else {
            const float* Af = (const float*)Av + (long long)bz * aStride;
            float4 a4 = *(const float4*)&Af[(long long)(m0 + lr) * lda + k0 + lk];
            As[lk + 0][lr] = a4.x;
            As[lk + 1][lr] = a4.y;
            As[lk + 2][lr] = a4.z;
            As[lk + 3][lr] = a4.w;
        }
        if (B_IS_NT) {
            float4 b4 = *(const float4*)&B[(long long)(n0 + lr) * ldb + k0 + lk];
            Bs[lk + 0][lr] = b4.x;
            Bs[lk + 1][lr] = b4.y;
            Bs[lk + 2][lr] = b4.z;
            Bs[lk + 3][lr] = b4.w;
        } else {
            const int bk = tid >> 4;
            const int bn = (tid & 15) * 4;
            float4 b4 = *(const float4*)&B[(long long)(k0 + bk) * ldb + n0 + bn];
            *(float4*)&Bs[bk][bn] = b4;
        }
        __syncthreads();

#pragma unroll
        for (int k = 0; k < 16; ++k) {
            float4 av = *(const float4*)&As[k][ty * 4];
            float4 bv = *(const float4*)&Bs[k][tx * 4];
            float am[4] = {av.x, av.y, av.z, av.w};
            float bm[4] = {bv.x, bv.y, bv.z, bv.w};
#pragma unroll
            for (int i = 0; i < 4; ++i)
#pragma unroll
                for (int j = 0; j < 4; ++j) acc[i][j] += am[i] * bm[j];
        }
        __syncthreads();
    }

#pragma unroll
    for (int i = 0; i < 4; ++i) {
        const long long m = m0 + ty * 4 + i;
        if (OUT_BF16) {
            __hip_bfloat16* Cb = (__hip_bfloat16*)Cv + (long long)bz * cStride;
            uint2 pv;
            pv.x = pack2bf(acc[i][0] * outScale, acc[i][1] * outScale);
            pv.y = pack2bf(acc[i][2] * outScale, acc[i][3] * outScale);
            *(uint2*)&Cb[m * ldc + n0 + tx * 4] = pv;
        } else {
            float* Cf = (float*)Cv + (long long)bz * cStride;
            float4 cv;
            cv.x = acc[i][0]; cv.y = acc[i][1]; cv.z = acc[i][2]; cv.w = acc[i][3];
            if (bias) {
                const int n = n0 + tx * 4;
                cv.x += bias[n + 0]; cv.y += bias[n + 1];
                cv.z += bias[n + 2]; cv.w += bias[n + 3];
            }
            *(float4*)&Cf[m * ldc + n0 + tx * 4] = cv;
        }
    }
}

// ---------------------------------------------------------------------------
// RoPE on q_raw[...,128:192] -> q_h[...,512:576] bf16, scale folded.
// ---------------------------------------------------------------------------
__global__ __launch_bounds__(256) void rope_q_kernel(
    const float* __restrict__ q_raw, const float* __restrict__ freqs,
    __hip_bfloat16* __restrict__ q_h)
{
    const int idx = blockIdx.x * 256 + threadIdx.x;
    const int i = idx & 31;
    const int h = (idx >> 5) & 15;
    const int s = (idx >> 9) & 2047;
    const int b = idx >> 20;
    const float f = freqs[s * 32 + i];
    float cs, sn;
    __sincosf(f, &sn, &cs);
    const int row = (b * S_ + s) * H_ + h;
    const float a = q_raw[row * QKHD_ + NOPE_ + 2 * i];
    const float bb = q_raw[row * QKHD_ + NOPE_ + 2 * i + 1];
    uint pv = pack2bf((a * cs - bb * sn) * SCALE_, (a * sn + bb * cs) * SCALE_);
    *(uint*)&q_h[(long long)row * 576 + 512 + 2 * i] = pv;
}

// ---------------------------------------------------------------------------
// kv post: rmsnorm(kv_raw[:,0:512]) and rope(kv_raw[:,512:576]) -> kv_h bf16.
// One wave per (b,s).
// ---------------------------------------------------------------------------
__global__ __launch_bounds__(64) void kv_post_kernel(
    const float* __restrict__ kv_raw, const float* __restrict__ w,
    const float* __restrict__ freqs, __hip_bfloat16* __restrict__ kv_h)
{
    const int bs = blockIdx.x;
    const int lane = threadIdx.x;
    const float* src = kv_raw + (long long)bs * 576;
    __hip_bfloat16* dst = kv_h + (long long)bs * 576;

    const int c = 4 * lane;
    float4 v0 = *(const float4*)&src[c];
    float4 v1 = *(const float4*)&src[256 + c];
    float ss = v0.x * v0.x + v0.y * v0.y + v0.z * v0.z + v0.w * v0.w +
               v1.x * v1.x + v1.y * v1.y + v1.z * v1.z + v1.w * v1.w;
#pragma unroll
    for (int o = 32; o; o >>= 1) ss += __shfl_xor(ss, o, 64);
    const float rs = rsqrtf(ss * (1.0f / 512.0f) + EPS_);

    float4 w0 = *(const float4*)&w[c];
    float4 w1 = *(const float4*)&w[256 + c];
    uint2 p0, p1;
    p0.x = pack2bf(v0.x * rs * w0.x, v0.y * rs * w0.y);
    p0.y = pack2bf(v0.z * rs * w0.z, v0.w * rs * w0.w);
    p1.x = pack2bf(v1.x * rs * w1.x, v1.y * rs * w1.y);
    p1.y = pack2bf(v1.z * rs * w1.z, v1.w * rs * w1.w);
    *(uint2*)&dst[c] = p0;
    *(uint2*)&dst[256 + c] = p1;

    if (lane < 32) {
        const int s = bs & 2047;
        const float f = freqs[s * 32 + lane];
        float cs, sn;
        __sincosf(f, &sn, &cs);
        const float a = src[512 + 2 * lane];
        const float b2 = src[512 + 2 * lane + 1];
        *(uint*)&dst[512 + 2 * lane] = pack2bf(a * cs - b2 * sn, a * sn + b2 * cs);
    }
}

// ---------------------------------------------------------------------------
// MFMA flash attention (latent space, causal).
// Block = 64 q rows of one (b,h); 4 waves x 16 rows. KV tile = 32 rows.
//  - S^T = K . Q^T via mfma_f32_16x16x32_bf16 (Q frags in regs, scale folded)
//  - online softmax in C-layout (col = q-row = lane&15 -> m,l lane-local)
//  - PV: O^T = V^T . P^T; P^T->B-operand via 8 shuffles; V^T staged as packed
//    t-pair dwords (stride 22 dw), in two 256-d halves to fit 64 KB LDS.
// ---------------------------------------------------------------------------
__global__ __launch_bounds__(256) void attn_kernel(
    const __hip_bfloat16* __restrict__ q_h,   // (B,S,H,576), q*scale
    const __hip_bfloat16* __restrict__ kv_h,  // (B,S,576)
    __hip_bfloat16* __restrict__ o_h)         // (B,S,H,512)
{
    __shared__ ushort kvs[32 * 584];   // row-major KV tile, 37376 B
    __shared__ uint   vts[256 * 22];   // V^T half-tile (t-pair dwords), 22528 B

    const int qt   = 31 - blockIdx.x;          // big blocks first
    const int h    = blockIdx.y;
    const int b    = blockIdx.z;
    const int tid  = threadIdx.x;
    const int wid  = tid >> 6;
    const int lane = tid & 63;
    const int m    = lane & 15;
    const int q4   = lane >> 4;
    const int row0 = qt * 64 + wid * 16;
    const int sRow = row0 + m;                 // this lane's q row

    union U4 { uint4 u; bf16x8 v; };

    // Q fragments: lane holds Q[sRow][k = 32f + 8*q4 + j]
    U4 qf[18];
    {
        const uint4* qp = (const uint4*)(q_h + ((long long)(b * S_ + sRow) * H_ + h) * 576);
#pragma unroll
        for (int f = 0; f < 18; ++f) qf[f].u = qp[f * 4 + q4];
    }

    f32x4 o[32];
#pragma unroll
    for (int c = 0; c < 32; ++c) o[c] = (f32x4){0.f, 0.f, 0.f, 0.f};
    float mrun = -3.0e38f, lrun = 0.0f;

    const uint4* kvg = (const uint4*)(kv_h + (long long)b * S_ * 576);
    const int qEnd = qt * 64 + 64;

    for (int t0 = 0; t0 < qEnd; t0 += 32) {
        __syncthreads();
        // ---- stage KV rows (32 x 576 bf16), row stride 584 halves
#pragma unroll
        for (int j = 0; j < 9; ++j) {
            int cch = tid + j * 256;
            int t = cch / 72, col = cch - t * 72;
            ((uint4*)kvs)[t * 73 + col] = kvg[(t0 + t) * 72 + col];
        }
        // ---- stage V^T half 0 (d 0..255): vts[d*22 + tp] = pack(V[2tp][d],V[2tp+1][d])
#pragma unroll
        for (int j = 0; j < 2; ++j) {
            int it = tid + j * 256;
            int tp = it & 15, dg = it >> 4;            // dg 0..31
            uint4 a = kvg[(t0 + 2 * tp) * 72 + dg];
            uint4 bq = kvg[(t0 + 2 * tp + 1) * 72 + dg];
            uint* vp = &vts[(dg * 8) * 22 + tp];
            vp[0 * 22] = (a.x & 0xffffu) | (bq.x << 16);
            vp[1 * 22] = (a.x >> 16)     | (bq.x & 0xffff0000u);
            vp[2 * 22] = (a.y & 0xffffu) | (bq.y << 16);
            vp[3 * 22] = (a.y >> 16)     | (bq.y & 0xffff0000u);
            vp[4 * 22] = (a.z & 0xffffu) | (bq.z << 16);
            vp[5 * 22] = (a.z >> 16)     | (bq.z & 0xffff0000u);
            vp[6 * 22] = (a.w & 0xffffu) | (bq.w << 16);
            vp[7 * 22] = (a.w >> 16)     | (bq.w & 0xffff0000u);
        }
        __syncthreads();

        const bool act = (t0 <= row0 + 15);    // wave-uniform causal skip
        float alpha = 1.0f;
        U4 bb;                                 // P^T B-fragment (bf16x8)
        if (act) {
            // ---- S^T = K . Q^T   (two 16-t subtiles)
            f32x4 st[2];
#pragma unroll
            for (int s = 0; s < 2; ++s) {
                f32x4 acc = (f32x4){0.f, 0.f, 0.f, 0.f};
                const int trow = s * 16 + m;
#pragma unroll
                for (int f = 0; f < 18; ++f) {
                    U4 a; a.u = ((const uint4*)kvs)[trow * 73 + f * 4 + q4];
                    acc = __builtin_amdgcn_mfma_f32_16x16x32_bf16(a.v, qf[f].v, acc, 0, 0, 0);
                }
                st[s] = acc;
            }
            // ---- mask + online softmax (per q-column m; lane-local state)
            float p[2][4];
            float vmax = -3.0e38f;
#pragma unroll
            for (int s = 0; s < 2; ++s)
#pragma unroll
                for (int r = 0; r < 4; ++r) {
                    int t = t0 + s * 16 + q4 * 4 + r;
                    float v = (t <= sRow) ? st[s][r] : -3.0e38f;
                    p[s][r] = v;
                    vmax = fmaxf(vmax, v);
                }
            vmax = fmaxf(vmax, __shfl_xor(vmax, 16, 64));
            vmax = fmaxf(vmax, __shfl_xor(vmax, 32, 64));
            const float mnew = fmaxf(mrun, vmax);
            alpha = __expf(mrun - mnew);
            float tsum = 0.f;
#pragma unroll
            for (int s = 0; s < 2; ++s)
#pragma unroll
                for (int r = 0; r < 4; ++r) {
                    p[s][r] = __expf(p[s][r] - mnew);
                    tsum += p[s][r];
                }
            tsum += __shfl_xor(tsum, 16, 64);
            tsum += __shfl_xor(tsum, 32, 64);
            mrun = mnew;
            lrun = lrun * alpha + tsum;

            // ---- pack P to bf16 pairs, build PV B-fragment via shuffles
            uint pk00 = pack2bf(p[0][0], p[0][1]);
            uint pk01 = pack2bf(p[0][2], p[0][3]);
            uint pk10 = pack2bf(p[1][0], p[1][1]);
            uint pk11 = pack2bf(p[1][2], p[1][3]);
            const int srcA = ((lane >> 4) & 1) * 32 + m;
            const int srcB = srcA + 16;
            uint a00 = (uint)__shfl((int)pk00, srcA, 64);
            uint a01 = (uint)__shfl((int)pk01, srcA, 64);
            uint a10 = (uint)__shfl((int)pk10, srcA, 64);
            uint a11 = (uint)__shfl((int)pk11, srcA, 64);
            uint b00 = (uint)__shfl((int)pk00, srcB, 64);
            uint b01 = (uint)__shfl((int)pk01, srcB, 64);
            uint b10 = (uint)__shfl((int)pk10, srcB, 64);
            uint b11 = (uint)__shfl((int)pk11, srcB, 64);
            const bool hi2 = (lane >> 5) & 1;          // tsub select
            bb.u.x = hi2 ? a10 : a00;
            bb.u.y = hi2 ? a11 : a01;
            bb.u.z = hi2 ? b10 : b00;
            bb.u.w = hi2 ? b11 : b01;

            // ---- PV pass 1: d 0..255
#pragma unroll
            for (int c = 0; c < 16; ++c) {
                const uint* vrow = &vts[(c * 16 + m) * 22 + q4 * 4];
                uint2 lo = *(const uint2*)vrow;
                uint2 hi = *(const uint2*)(vrow + 2);
                U4 av; av.u = make_uint4(lo.x, lo.y, hi.x, hi.y);
                o[c].x *= alpha; o[c].y *= alpha; o[c].z *= alpha; o[c].w *= alpha;
                o[c] = __builtin_amdgcn_mfma_f32_16x16x32_bf16(av.v, bb.v, o[c], 0, 0, 0);
            }
        }
        __syncthreads();
        // ---- stage V^T half 1 (d 256..511)
#pragma unroll
        for (int j = 0; j < 2; ++j) {
            int it = tid + j * 256;
            int tp = it & 15, dg = it >> 4;
            uint4 a = kvg[(t0 + 2 * tp) * 72 + 32 + dg];
            uint4 bq = kvg[(t0 + 2 * tp + 1) * 72 + 32 + dg];
            uint* vp = &vts[(dg * 8) * 22 + tp];
            vp[0 * 22] = (a.x & 0xffffu) | (bq.x << 16);
            vp[1 * 22] = (a.x >> 16)     | (bq.x & 0xffff0000u);
            vp[2 * 22] = (a.y & 0xffffu) | (bq.y << 16);
            vp[3 * 22] = (a.y >> 16)     | (bq.y & 0xffff0000u);
            vp[4 * 22] = (a.z & 0xffffu) | (bq.z << 16);
            vp[5 * 22] = (a.z >> 16)     | (bq.z & 0xffff0000u);
            vp[6 * 22] = (a.w & 0xffffu) | (bq.w << 16);
            vp[7 * 22] = (a.w >> 16)     | (bq.w & 0xffff0000u);
        }
        __syncthreads();
        if (act) {
            // ---- PV pass 2: d 256..511
#pragma unroll
            for (int c = 16; c < 32; ++c) {
                const uint* vrow = &vts[((c - 16) * 16 + m) * 22 + q4 * 4];
                uint2 lo = *(const uint2*)vrow;
                uint2 hi = *(const uint2*)(vrow + 2);
                U4 av; av.u = make_uint4(lo.x, lo.y, hi.x, hi.y);
                o[c].x *= alpha; o[c].y *= alpha; o[c].z *= alpha; o[c].w *= alpha;
                o[c] = __builtin_amdgcn_mfma_f32_16x16x32_bf16(av.v, bb.v, o[c], 0, 0, 0);
            }
        }
    }

    // ---- epilogue: lane holds O^T[d = 16c + 4*q4 + r][m]; normalize, store bf16
    const float inv = 1.0f / lrun;
    __hip_bfloat16* op = o_h + ((long long)(b * S_ + sRow) * H_ + h) * 512;
#pragma unroll
    for (int c = 0; c < 32; ++c) {
        uint2 pv;
        pv.x = pack2bf(o[c].x * inv, o[c].y * inv);
        pv.y = pack2bf(o[c].z * inv, o[c].w * inv);
        *(uint2*)&op[c * 16 + q4 * 4] = pv;
    }
}

// ---------------------------------------------------------------------------
extern "C" void kernel_launch(void* const* d_in, const int* in_sizes, int n_in,
                              void* d_out, int out_size, void* d_ws, size_t ws_size,
                              hipStream_t stream)
{
    const float* x         = (const float*)d_in[0];
    const float* freqs     = (const float*)d_in[1];
    // d_in[2] = mask (unused: causal handled analytically)
    const float* wq_w      = (const float*)d_in[3];
    const float* wq_b      = (const float*)d_in[4];
    const float* wkv_a_w   = (const float*)d_in[5];
    const float* wkv_a_b   = (const float*)d_in[6];
    const float* kv_norm_w = (const float*)d_in[7];
    const float* wkv_b_w   = (const float*)d_in[8];
    const float* wo_w      = (const float*)d_in[9];
    const float* wo_b      = (const float*)d_in[10];
    float* out = (float*)d_out;

    // Workspace (floats). R0: q_raw(12.58M)+kv_raw alias; later o_h bf16 alias.
    float* ws = (float*)d_ws;
    float* R0      = ws;                        // 16,777,216 floats
    float* q_raw   = R0;                        // (B,S,H,192) f32
    float* kv_raw  = R0 + 12582912LL;           // (B,S,576)  f32
    __hip_bfloat16* o_h = (__hip_bfloat16*)R0;  // (B,S,H,512) bf16 (after q dead)
    __hip_bfloat16* q_h = (__hip_bfloat16*)(R0 + 16777216LL);  // (B,S,H,576) bf16
    float* out_v   = R0 + 16777216LL;           // (B,S,H,128) f32, aliases q_h (dead)
    __hip_bfloat16* kv_h = (__hip_bfloat16*)(R0 + 16777216LL + 18874368LL); // (B,S,576)
    // total: 16,777,216 + 18,874,368 + 1,179,648 = 36,831,232 floats = 147.3 MB

    dim3 blk(256);

    // 1) q_raw = x @ wq_w^T + wq_b
    gemm_kernel<true, false, false><<<dim3(48, 64, 1), blk, 0, stream>>>(
        x, 2048, 0LL, wq_w, 2048, 0LL, wq_b, 1.0f, q_raw, 3072, 0LL, 2048);

    // 2) kv_raw = x @ wkv_a_w^T + wkv_a_b
    gemm_kernel<true, false, false><<<dim3(9, 64, 1), blk, 0, stream>>>(
        x, 2048, 0LL, wkv_a_w, 2048, 0LL, wkv_a_b, 1.0f, kv_raw, 576, 0LL, 2048);

    // 3) RoPE(q) -> q_h[...,512:576] bf16, scale folded
    rope_q_kernel<<<dim3(8192), blk, 0, stream>>>(q_raw, freqs, q_h);

    // 4) rmsnorm+rope -> kv_h bf16
    kv_post_kernel<<<dim3(4096), dim3(64), 0, stream>>>(kv_raw, kv_norm_w, freqs, kv_h);

    // 5) q_h[...,0:512] = (q_nope @ wkv_b[h,:128,:]) * scale, bf16 out
    gemm_kernel<false, false, true><<<dim3(8, 64, 16), blk, 0, stream>>>(
        q_raw, 3072, 192LL, wkv_b_w, 512, 131072LL, nullptr, SCALE_,
        q_h, 9216, 576LL, 128);

    // 6) MFMA flash attention -> o_h bf16
    attn_kernel<<<dim3(32, 16, 2), blk, 0, stream>>>(q_h, kv_h, o_h);

    // 7) out_v = attn @ wkv_b[h,128:,:]^T  (bf16 A)
    gemm_kernel<true, true, false><<<dim3(2, 64, 16), blk, 0, stream>>>(
        o_h, 8192, 512LL, wkv_b_w + 65536, 512, 131072LL, nullptr, 1.0f,
        out_v, 2048, 128LL, 512);

    // 8) out = out_v @ wo_w^T + wo_b
    gemm_kernel<true, false, false><<<dim3(32, 64, 1), blk, 0, stream>>>(
        out_v, 2048, 0LL, wo_w, 2048, 0LL, wo_b, 1.0f, out, 2048, 0LL, 2048);
}

// Round 3
// 1850.756 us; speedup vs baseline: 9.2229x; 1.7609x over previous
//
#include <hip/hip_runtime.h>
#include <hip/hip_bf16.h>
#include <math.h>

// MLA forward: B=2, S=2048, D=2048, H=16, KV_RANK=512, NOPE=128, ROPE=64
#define B_ 2
#define S_ 2048
#define H_ 16
#define SCALE_ 0.07216878364870323f   // 192^-0.5
#define EPS_ 1.1920929e-07f

typedef __attribute__((ext_vector_type(8))) short bf16x8;
typedef __attribute__((ext_vector_type(4))) float f32x4;
union U4 { uint4 u; bf16x8 v; };

__device__ __forceinline__ uint bfbits(float x) {   // f32 -> bf16 bits, RNE
    uint u = __float_as_uint(x);
    return (u + 0x7fffu + ((u >> 16) & 1u)) >> 16;
}
__device__ __forceinline__ uint pack2bf(float a, float b) {
    return bfbits(a) | (bfbits(b) << 16);
}
__device__ __forceinline__ void gld_lds16(const ushort* g, ushort* l) {
    // async global->LDS, 16B per lane; LDS dest = wave-uniform base + lane*16
    __builtin_amdgcn_global_load_lds(
        (const __attribute__((address_space(1))) uint*)g,
        (__attribute__((address_space(3))) uint*)l, 16, 0, 0);
}

// ---------------------------------------------------------------------------
// MFMA bf16 GEMM (NT): C[m,n] = scale * sum_k A[m,k]*B[n,k] + bias[n]
// 128x128 tile, BK=32, 256 thr (4 waves 2x2 of 64x64), 16x16x32 MFMA.
// global_load_lds staging with source-address XOR swizzle so fragment
// b128 reads are 2-way-max bank conflicts. M,N,K all % 128/128/32 == 0.
// ---------------------------------------------------------------------------
template<bool OUT_BF16>
__global__ __launch_bounds__(256) void mgemm(
    const ushort* __restrict__ A, int lda, long long aOff,
    const ushort* __restrict__ Bm, int ldb, long long bOff,
    const float* __restrict__ bias, float scale,
    void* __restrict__ Cv, int ldc, long long cOff, int K)
{
    __shared__ ushort As[128 * 32];
    __shared__ ushort Bs[128 * 32];

    const int z = blockIdx.z;
    A  += (long long)z * aOff;
    Bm += (long long)z * bOff;

    const int n0 = blockIdx.x * 128;
    const int m0 = blockIdx.y * 128;
    const int tid = threadIdx.x;
    const int w   = tid >> 6;
    const int l   = tid & 63;
    const int m   = l & 15;
    const int q4  = l >> 4;
    const int mw  = (w & 1) * 64;
    const int nw  = (w >> 1) * 64;
    const int sr  = l >> 2;          // staging: row within 16-row slot
    const int sc  = l & 3;           // staging: col8 slot

    f32x4 acc[4][4];
#pragma unroll
    for (int i = 0; i < 4; ++i)
#pragma unroll
        for (int j = 0; j < 4; ++j) acc[i][j] = (f32x4){0.f, 0.f, 0.f, 0.f};

    for (int k0 = 0; k0 < K; k0 += 32) {
#pragma unroll
        for (int jj = 0; jj < 2; ++jj) {
            const int slot = w * 2 + jj;              // 0..7
            const int row  = slot * 16 + sr;
            const int g    = sc ^ ((row >> 1) & 3);   // source col-group swizzle
            gld_lds16(&A[(long long)(m0 + row) * lda + k0 + g * 8], &As[slot * 512]);
            gld_lds16(&Bm[(long long)(n0 + row) * ldb + k0 + g * 8], &Bs[slot * 512]);
        }
        __syncthreads();

        U4 af[4], bf[4];
#pragma unroll
        for (int i = 0; i < 4; ++i) {
            const int ra = mw + i * 16 + m;
            af[i].u = *(const uint4*)&As[ra * 32 + (q4 ^ ((ra >> 1) & 3)) * 8];
            const int rb = nw + i * 16 + m;
            bf[i].u = *(const uint4*)&Bs[rb * 32 + (q4 ^ ((rb >> 1) & 3)) * 8];
        }
#pragma unroll
        for (int i = 0; i < 4; ++i)
#pragma unroll
            for (int j = 0; j < 4; ++j)
                acc[i][j] = __builtin_amdgcn_mfma_f32_16x16x32_bf16(
                    af[i].v, bf[j].v, acc[i][j], 0, 0, 0);
        __syncthreads();
    }

#pragma unroll
    for (int j = 0; j < 4; ++j) {
        const int cn = n0 + nw + j * 16 + m;
        const float bv = bias ? bias[cn] : 0.0f;
#pragma unroll
        for (int i = 0; i < 4; ++i) {
            const int rw = m0 + mw + i * 16 + q4 * 4;
#pragma unroll
            for (int r = 0; r < 4; ++r) {
                const float val = acc[i][j][r] * scale + bv;
                if (OUT_BF16)
                    ((ushort*)Cv)[(long long)z * cOff + (long long)(rw + r) * ldc + cn] =
                        (ushort)bfbits(val);
                else
                    ((float*)Cv)[(long long)z * cOff + (long long)(rw + r) * ldc + cn] = val;
            }
        }
    }
}

// ---------------------------------------------------------------------------
// f32 -> bf16 converters
// ---------------------------------------------------------------------------
__global__ __launch_bounds__(256) void conv_bf16(
    const float* __restrict__ s, ushort* __restrict__ d)
{
    const long long i = ((long long)blockIdx.x * 256 + threadIdx.x) * 4;
    float4 v = *(const float4*)&s[i];
    uint2 p; p.x = pack2bf(v.x, v.y); p.y = pack2bf(v.z, v.w);
    *(uint2*)&d[i] = p;
}

// wkv_a_w (576,2048) -> padded (640,2048) bf16, zero rows 576..639
__global__ __launch_bounds__(256) void conv_wkva(
    const float* __restrict__ s, ushort* __restrict__ d)
{
    const int i = (blockIdx.x * 256 + threadIdx.x) * 4;   // < 640*2048
    const int r = i >> 11;
    uint2 p = make_uint2(0u, 0u);
    if (r < 576) {
        float4 v = *(const float4*)&s[i];
        p.x = pack2bf(v.x, v.y); p.y = pack2bf(v.z, v.w);
    }
    *(uint2*)&d[i] = p;
}

// wkv_b nope half: W(16,256,512)[:, :128, :] -> T(16,512,128) bf16 (transposed)
__global__ __launch_bounds__(256) void conv_wkvb_t(
    const float* __restrict__ Wsrc, ushort* __restrict__ T)
{
    __shared__ float tile[32][33];
    const int h = blockIdx.z, dt = blockIdx.y, ct = blockIdx.x;
    const int tx = threadIdx.x & 31, ty = threadIdx.x >> 5;
#pragma unroll
    for (int p8 = 0; p8 < 4; ++p8) {
        const int dd = dt * 32 + ty + p8 * 8;
        tile[ty + p8 * 8][tx] = Wsrc[((long long)(h * 256 + dd)) * 512 + ct * 32 + tx];
    }
    __syncthreads();
#pragma unroll
    for (int p8 = 0; p8 < 4; ++p8) {
        const int cc = ct * 32 + ty + p8 * 8;
        T[((long long)h * 512 + cc) * 128 + dt * 32 + tx] =
            (ushort)bfbits(tile[tx][ty + p8 * 8]);
    }
}

// wkv_b v half: W(16,256,512)[:, 128:, :] -> V(16,128,512) bf16
__global__ __launch_bounds__(256) void conv_wkvbv(
    const float* __restrict__ Wsrc, ushort* __restrict__ V)
{
    const int i = (blockIdx.x * 256 + threadIdx.x) * 4;   // < 16*128*512
    const int h = i >> 16;
    const int rem = i & 65535;
    float4 v = *(const float4*)&Wsrc[((long long)(h * 256 + 128)) * 512 + rem];
    uint2 p; p.x = pack2bf(v.x, v.y); p.y = pack2bf(v.z, v.w);
    *(uint2*)&V[i] = p;
}

// q_raw (bs, h*192+d) f32 -> qn (bs, h*128+d) bf16  (nope cols only)
__global__ __launch_bounds__(256) void conv_qn(
    const float* __restrict__ q_raw, ushort* __restrict__ qn)
{
    const int i = (blockIdx.x * 256 + threadIdx.x) * 4;   // < 4096*2048
    const int bs = i >> 11;
    const int c = i & 2047;
    const int hh = c >> 7, d = c & 127;
    float4 v = *(const float4*)&q_raw[(long long)bs * 3072 + hh * 192 + d];
    uint2 p; p.x = pack2bf(v.x, v.y); p.y = pack2bf(v.z, v.w);
    *(uint2*)&qn[i] = p;
}

// ---------------------------------------------------------------------------
// RoPE on q_raw[...,128:192] -> q_h[...,512:576] bf16, scale folded.
// ---------------------------------------------------------------------------
__global__ __launch_bounds__(256) void rope_q_kernel(
    const float* __restrict__ q_raw, const float* __restrict__ freqs,
    ushort* __restrict__ q_h)
{
    const int idx = blockIdx.x * 256 + threadIdx.x;
    const int i = idx & 31;
    const int h = (idx >> 5) & 15;
    const int s = (idx >> 9) & 2047;
    const int b = idx >> 20;
    const float f = freqs[s * 32 + i];
    float cs, sn;
    __sincosf(f, &sn, &cs);
    const int row = (b * S_ + s) * H_ + h;
    const float a  = q_raw[(long long)row * 192 + 128 + 2 * i];
    const float bb = q_raw[(long long)row * 192 + 128 + 2 * i + 1];
    *(uint*)&q_h[(long long)row * 576 + 512 + 2 * i] =
        pack2bf((a * cs - bb * sn) * SCALE_, (a * sn + bb * cs) * SCALE_);
}

// ---------------------------------------------------------------------------
// kv post: bias add + rmsnorm(kv[:512]) and rope(kv[512:576]) -> kv_h bf16.
// kv_raw has padded row stride 640. One wave per (b,s).
// ---------------------------------------------------------------------------
__global__ __launch_bounds__(64) void kv_post_kernel(
    const float* __restrict__ kv_raw, const float* __restrict__ bias,
    const float* __restrict__ w, const float* __restrict__ freqs,
    ushort* __restrict__ kv_h)
{
    const int bs = blockIdx.x;
    const int lane = threadIdx.x;
    const float* src = kv_raw + (long long)bs * 640;
    ushort* dst = kv_h + (long long)bs * 576;

    const int c = 4 * lane;
    float4 v0 = *(const float4*)&src[c];
    float4 v1 = *(const float4*)&src[256 + c];
    float4 b0 = *(const float4*)&bias[c];
    float4 b1 = *(const float4*)&bias[256 + c];
    v0.x += b0.x; v0.y += b0.y; v0.z += b0.z; v0.w += b0.w;
    v1.x += b1.x; v1.y += b1.y; v1.z += b1.z; v1.w += b1.w;
    float ss = v0.x * v0.x + v0.y * v0.y + v0.z * v0.z + v0.w * v0.w +
               v1.x * v1.x + v1.y * v1.y + v1.z * v1.z + v1.w * v1.w;
#pragma unroll
    for (int o = 32; o; o >>= 1) ss += __shfl_xor(ss, o, 64);
    const float rs = rsqrtf(ss * (1.0f / 512.0f) + EPS_);

    float4 w0 = *(const float4*)&w[c];
    float4 w1 = *(const float4*)&w[256 + c];
    uint2 p0, p1;
    p0.x = pack2bf(v0.x * rs * w0.x, v0.y * rs * w0.y);
    p0.y = pack2bf(v0.z * rs * w0.z, v0.w * rs * w0.w);
    p1.x = pack2bf(v1.x * rs * w1.x, v1.y * rs * w1.y);
    p1.y = pack2bf(v1.z * rs * w1.z, v1.w * rs * w1.w);
    *(uint2*)&dst[c] = p0;
    *(uint2*)&dst[256 + c] = p1;

    if (lane < 32) {
        const int s = bs & 2047;
        const float f = freqs[s * 32 + lane];
        float cs, sn;
        __sincosf(f, &sn, &cs);
        const float a  = src[512 + 2 * lane]     + bias[512 + 2 * lane];
        const float b2 = src[512 + 2 * lane + 1] + bias[512 + 2 * lane + 1];
        *(uint*)&dst[512 + 2 * lane] = pack2bf(a * cs - b2 * sn, a * sn + b2 * cs);
    }
}

// ---------------------------------------------------------------------------
// MFMA flash attention v3 (latent space, causal).
// Block = 32 q rows of one (b,h); 4 waves = (2 q-groups of 16) x (2 d-halves).
// KV tile = 32 t. Per tile:
//   - V^T staged to LDS (stride 20 dw, XOR swizzle: conflict-free b128 r/w)
//   - S^T partials: K fragments read DIRECTLY from global (L2-hot), k split
//     across the d-half wave pair; partials summed via small LDS exchange
//   - online softmax in C-layout (lane-local m,l per q-col)
//   - P^T -> PV B-fragment via 8 shuffles; PV over this wave's 256-d half
// 2 barriers/tile. O accum = 64 VGPRs; ~150 VGPR total -> 3 waves/SIMD.
// ---------------------------------------------------------------------------
__global__ __launch_bounds__(256, 3) void attn_kernel(
    const ushort* __restrict__ q_h,   // (B,S,H,576), q*scale
    const ushort* __restrict__ kv_h,  // (B,S,576)
    ushort* __restrict__ o_h)         // (B,S,H,512)
{
    __shared__ uint  vts[512 * 20];       // V^T tile, 40960 B
    __shared__ float sPart[4][64][8];     // S^T partial exchange, 8192 B

    const int qb   = 63 - (int)blockIdx.x;   // big blocks first
    const int h    = blockIdx.y;
    const int b    = blockIdx.z;
    const int tid  = threadIdx.x;
    const int wid  = tid >> 6;
    const int lane = tid & 63;
    const int m    = lane & 15;
    const int q4   = lane >> 4;
    const int qg   = wid & 1;
    const int dh   = wid >> 1;
    const int row0 = qb * 32 + qg * 16;
    const int sRow = row0 + m;

    // Q fragments for this wave's k-half (dh*288 .. dh*288+287)
    U4 qf[9];
    {
        const uint4* qp = (const uint4*)(q_h + ((long long)(b * S_ + sRow) * H_ + h) * 576);
#pragma unroll
        for (int f = 0; f < 9; ++f) qf[f].u = qp[dh * 36 + f * 4 + q4];
    }

    f32x4 o[16];
#pragma unroll
    for (int c = 0; c < 16; ++c) o[c] = (f32x4){0.f, 0.f, 0.f, 0.f};
    float mrun = -3.0e38f, lrun = 0.0f;

    const ushort* kvb = kv_h + (long long)b * S_ * 576;
    const int nT = qb + 1;

    for (int it = 0; it < nT; ++it) {
        const int t0 = it * 32;
        __syncthreads();   // vts/sPart safe to overwrite

        // ---- stage V^T: vts[d*20 + (tp ^ ((d>>3)&3)<<2)] = pack(V[2tp][d],V[2tp+1][d])
#pragma unroll
        for (int jj = 0; jj < 4; ++jj) {
            const int idx = tid + jj * 256;
            const int tp = idx & 15;
            const int dg = idx >> 4;          // 0..63 (8 d per thread)
            const uint4 a = *(const uint4*)&kvb[(t0 + 2 * tp) * 576 + dg * 8];
            const uint4 c = *(const uint4*)&kvb[(t0 + 2 * tp + 1) * 576 + dg * 8];
            uint* vp = &vts[(dg * 8) * 20 + (tp ^ ((dg & 3) << 2))];
            vp[0 * 20] = (a.x & 0xffffu) | (c.x << 16);
            vp[1 * 20] = (a.x >> 16)     | (c.x & 0xffff0000u);
            vp[2 * 20] = (a.y & 0xffffu) | (c.y << 16);
            vp[3 * 20] = (a.y >> 16)     | (c.y & 0xffff0000u);
            vp[4 * 20] = (a.z & 0xffffu) | (c.z << 16);
            vp[5 * 20] = (a.z >> 16)     | (c.z & 0xffff0000u);
            vp[6 * 20] = (a.w & 0xffffu) | (c.w << 16);
            vp[7 * 20] = (a.w >> 16)     | (c.w & 0xffff0000u);
        }

        // ---- S^T partials over this wave's k-half (K from global, L2-hot)
        f32x4 st[2];
#pragma unroll
        for (int s = 0; s < 2; ++s) {
            f32x4 a2 = (f32x4){0.f, 0.f, 0.f, 0.f};
            const uint4* kp = (const uint4*)&kvb[(t0 + s * 16 + m) * 576];
#pragma unroll
            for (int f = 0; f < 9; ++f) {
                U4 a; a.u = kp[dh * 36 + f * 4 + q4];
                a2 = __builtin_amdgcn_mfma_f32_16x16x32_bf16(a.v, qf[f].v, a2, 0, 0, 0);
            }
            st[s] = a2;
        }
        *(f32x4*)&sPart[wid][lane][0] = st[0];
        *(f32x4*)&sPart[wid][lane][4] = st[1];
        __syncthreads();
        {
            const int pw = wid ^ 2;
            f32x4 e0 = *(const f32x4*)&sPart[pw][lane][0];
            f32x4 e1 = *(const f32x4*)&sPart[pw][lane][4];
            st[0] = st[0] + e0;
            st[1] = st[1] + e1;
        }

        // ---- mask + online softmax (q-col = m, lane-local state)
        float p[2][4];
        float vmax = -3.0e38f;
#pragma unroll
        for (int s = 0; s < 2; ++s)
#pragma unroll
            for (int r = 0; r < 4; ++r) {
                const int t = t0 + s * 16 + q4 * 4 + r;
                const float v = (t <= sRow) ? st[s][r] : -3.0e38f;
                p[s][r] = v;
                vmax = fmaxf(vmax, v);
            }
        vmax = fmaxf(vmax, __shfl_xor(vmax, 16, 64));
        vmax = fmaxf(vmax, __shfl_xor(vmax, 32, 64));
        const float mnew = fmaxf(mrun, vmax);
        const float alpha = __expf(mrun - mnew);
        float tsum = 0.f;
#pragma unroll
        for (int s = 0; s < 2; ++s)
#pragma unroll
            for (int r = 0; r < 4; ++r) {
                p[s][r] = __expf(p[s][r] - mnew);
                tsum += p[s][r];
            }
        tsum += __shfl_xor(tsum, 16, 64);
        tsum += __shfl_xor(tsum, 32, 64);
        mrun = mnew;
        lrun = lrun * alpha + tsum;

        // ---- P^T -> PV B-fragment (k = 8*q4+j over t) via 8 shuffles
        U4 bb;
        {
            uint pk00 = pack2bf(p[0][0], p[0][1]);
            uint pk01 = pack2bf(p[0][2], p[0][3]);
            uint pk10 = pack2bf(p[1][0], p[1][1]);
            uint pk11 = pack2bf(p[1][2], p[1][3]);
            const int srcA = ((lane >> 4) & 1) * 32 + m;
            const int srcB = srcA + 16;
            uint a00 = (uint)__shfl((int)pk00, srcA, 64);
            uint a01 = (uint)__shfl((int)pk01, srcA, 64);
            uint a10 = (uint)__shfl((int)pk10, srcA, 64);
            uint a11 = (uint)__shfl((int)pk11, srcA, 64);
            uint b00 = (uint)__shfl((int)pk00, srcB, 64);
            uint b01 = (uint)__shfl((int)pk01, srcB, 64);
            uint b10 = (uint)__shfl((int)pk10, srcB, 64);
            uint b11 = (uint)__shfl((int)pk11, srcB, 64);
            const bool hi2 = (lane >> 5) & 1;
            bb.u.x = hi2 ? a10 : a00;
            bb.u.y = hi2 ? a11 : a01;
            bb.u.z = hi2 ? b10 : b00;
            bb.u.w = hi2 ? b11 : b01;
        }

        // ---- PV over this wave's 256-d half
#pragma unroll
        for (int c = 0; c < 16; ++c) {
            const int d = dh * 256 + c * 16 + m;
            U4 av;
            av.u = *(const uint4*)&vts[d * 20 + ((q4 * 4) ^ (((d >> 3) & 3) << 2))];
            o[c].x *= alpha; o[c].y *= alpha; o[c].z *= alpha; o[c].w *= alpha;
            o[c] = __builtin_amdgcn_mfma_f32_16x16x32_bf16(av.v, bb.v, o[c], 0, 0, 0);
        }
    }

    // ---- epilogue: lane holds O^T[d = dh*256+16c+4q4+r][q=m]
    const float inv = 1.0f / lrun;
    ushort* op = o_h + ((long long)(b * S_ + sRow) * H_ + h) * 512;
#pragma unroll
    for (int c = 0; c < 16; ++c) {
        uint2 pv;
        pv.x = pack2bf(o[c].x * inv, o[c].y * inv);
        pv.y = pack2bf(o[c].z * inv, o[c].w * inv);
        *(uint2*)&op[dh * 256 + c * 16 + q4 * 4] = pv;
    }
}

// ---------------------------------------------------------------------------
extern "C" void kernel_launch(void* const* d_in, const int* in_sizes, int n_in,
                              void* d_out, int out_size, void* d_ws, size_t ws_size,
                              hipStream_t stream)
{
    const float* x         = (const float*)d_in[0];
    const float* freqs     = (const float*)d_in[1];
    // d_in[2] = mask (unused: causal handled analytically)
    const float* wq_w      = (const float*)d_in[3];
    const float* wq_b      = (const float*)d_in[4];
    const float* wkv_a_w   = (const float*)d_in[5];
    const float* wkv_a_b   = (const float*)d_in[6];
    const float* kv_norm_w = (const float*)d_in[7];
    const float* wkv_b_w   = (const float*)d_in[8];
    const float* wo_w      = (const float*)d_in[9];
    const float* wo_b      = (const float*)d_in[10];
    float* out = (float*)d_out;

    // ---- workspace layout (202.4 MB)
    char* w = (char*)d_ws;
    ushort* x_bf    = (ushort*)w;  w += 16777216;   // (4096,2048) bf16
    ushort* wq_bf   = (ushort*)w;  w += 12582912;   // (3072,2048) bf16
    ushort* wkva_bf = (ushort*)w;  w += 2621440;    // (640,2048)  bf16 padded
    ushort* wo_bf   = (ushort*)w;  w += 8388608;    // (2048,2048) bf16
    ushort* wkvbT   = (ushort*)w;  w += 2097152;    // (16,512,128) bf16
    ushort* wkvbV   = (ushort*)w;  w += 2097152;    // (16,128,512) bf16
    float*  kv_raw  = (float*)w;   w += 10485760;   // (4096,640)  f32
    ushort* kv_h    = (ushort*)w;  w += 4718592;    // (4096,576)  bf16
    char* RA = w;                  w += 67108864;
    float*  q_raw = (float*)RA;                     // (4096,3072) f32
    ushort* qn_bf = (ushort*)(RA + 50331648);       // (4096,2048) bf16
    ushort* o_h   = (ushort*)RA;                    // (4096,8192) bf16 (q dead)
    char* RB = w;                  w += 75497472;
    ushort* q_h  = (ushort*)RB;                     // (4096,9216) bf16
    ushort* outv = (ushort*)RB;                     // (4096,2048) bf16 (q_h dead)

    dim3 blk(256);

    // ---- bf16 conversions
    conv_bf16 <<<dim3(8192), blk, 0, stream>>>(x, x_bf);         // 8.39M
    conv_bf16 <<<dim3(6144), blk, 0, stream>>>(wq_w, wq_bf);     // 6.29M
    conv_wkva <<<dim3(1280), blk, 0, stream>>>(wkv_a_w, wkva_bf);
    conv_bf16 <<<dim3(4096), blk, 0, stream>>>(wo_w, wo_bf);     // 4.19M
    conv_wkvb_t<<<dim3(16, 4, 16), blk, 0, stream>>>(wkv_b_w, wkvbT);
    conv_wkvbv <<<dim3(1024), blk, 0, stream>>>(wkv_b_w, wkvbV);

    // 1) q_raw = x @ wq_w^T + wq_b   (M=4096, N=3072, K=2048)
    mgemm<false><<<dim3(24, 32, 1), blk, 0, stream>>>(
        x_bf, 2048, 0LL, wq_bf, 2048, 0LL, wq_b, 1.0f, q_raw, 3072, 0LL, 2048);

    // 2) kv_raw = x @ wkv_a_w^T   (N=640 padded; bias folded into kv_post)
    mgemm<false><<<dim3(5, 32, 1), blk, 0, stream>>>(
        x_bf, 2048, 0LL, wkva_bf, 2048, 0LL, nullptr, 1.0f, kv_raw, 640, 0LL, 2048);

    // 3) RoPE(q_pe) -> q_h[...,512:576], scale folded
    rope_q_kernel<<<dim3(8192), blk, 0, stream>>>(q_raw, freqs, q_h);
    // 3b) q_nope -> packed bf16
    conv_qn<<<dim3(8192), blk, 0, stream>>>(q_raw, qn_bf);

    // 4) bias + rmsnorm + rope -> kv_h
    kv_post_kernel<<<dim3(4096), dim3(64), 0, stream>>>(
        kv_raw, wkv_a_b, kv_norm_w, freqs, kv_h);

    // 5) q_h[...,0:512] = (q_nope @ wkv_b[h,:128,:]) * scale  (M=4096,N=512,K=128 x16)
    mgemm<true><<<dim3(4, 32, 16), blk, 0, stream>>>(
        qn_bf, 2048, 128LL, wkvbT, 128, 65536LL, nullptr, SCALE_,
        q_h, 9216, 576LL, 128);

    // 6) MFMA flash attention -> o_h
    attn_kernel<<<dim3(64, 16, 2), blk, 0, stream>>>(q_h, kv_h, o_h);

    // 7) outv = attn @ wkv_b[h,128:,:]^T  (M=4096,N=128,K=512 x16)
    mgemm<true><<<dim3(1, 32, 16), blk, 0, stream>>>(
        o_h, 8192, 512LL, wkvbV, 512, 65536LL, nullptr, 1.0f,
        outv, 2048, 128LL, 512);

    // 8) out = outv @ wo_w^T + wo_b   (M=4096, N=2048, K=2048)
    mgemm<false><<<dim3(16, 32, 1), blk, 0, stream>>>(
        outv, 2048, 0LL, wo_bf, 2048, 0LL, wo_b, 1.0f, out, 2048, 0LL, 2048);
}

// Round 4
// 948.684 us; speedup vs baseline: 17.9927x; 1.9509x over previous
//
#include <hip/hip_runtime.h>
#include <hip/hip_bf16.h>
#include <math.h>

// MLA forward: B=2, S=2048, D=2048, H=16, KV_RANK=512, NOPE=128, ROPE=64
#define B_ 2
#define S_ 2048
#define H_ 16
#define SCALE_ 0.07216878364870323f   // 192^-0.5
#define EPS_ 1.1920929e-07f

typedef __attribute__((ext_vector_type(8))) short bf16x8;
typedef __attribute__((ext_vector_type(4))) float f32x4;
union U4 { uint4 u; bf16x8 v; };

__device__ __forceinline__ uint bfbits(float x) {   // f32 -> bf16 bits, RNE
    uint u = __float_as_uint(x);
    return (u + 0x7fffu + ((u >> 16) & 1u)) >> 16;
}
__device__ __forceinline__ uint pack2bf(float a, float b) {
    return bfbits(a) | (bfbits(b) << 16);
}
__device__ __forceinline__ void gld_lds16(const ushort* g, ushort* l) {
    // async global->LDS, 16B per lane; LDS dest = wave-uniform base + lane*16
    __builtin_amdgcn_global_load_lds(
        (const __attribute__((address_space(1))) uint*)g,
        (__attribute__((address_space(3))) uint*)l, 16, 0, 0);
}

// ---------------------------------------------------------------------------
// MFMA bf16 GEMM (NT): C[m,n] = scale * sum_k A[m,k]*B[n,k] + bias[n]
// 128x128 tile, BK=32, 256 thr (4 waves 2x2 of 64x64), 16x16x32 MFMA.
// ---------------------------------------------------------------------------
template<bool OUT_BF16>
__global__ __launch_bounds__(256) void mgemm(
    const ushort* __restrict__ A, int lda, long long aOff,
    const ushort* __restrict__ Bm, int ldb, long long bOff,
    const float* __restrict__ bias, float scale,
    void* __restrict__ Cv, int ldc, long long cOff, int K)
{
    __shared__ ushort As[128 * 32];
    __shared__ ushort Bs[128 * 32];

    const int z = blockIdx.z;
    A  += (long long)z * aOff;
    Bm += (long long)z * bOff;

    const int n0 = blockIdx.x * 128;
    const int m0 = blockIdx.y * 128;
    const int tid = threadIdx.x;
    const int w   = tid >> 6;
    const int l   = tid & 63;
    const int m   = l & 15;
    const int q4  = l >> 4;
    const int mw  = (w & 1) * 64;
    const int nw  = (w >> 1) * 64;
    const int sr  = l >> 2;          // staging: row within 16-row slot
    const int sc  = l & 3;           // staging: col8 slot

    f32x4 acc[4][4];
#pragma unroll
    for (int i = 0; i < 4; ++i)
#pragma unroll
        for (int j = 0; j < 4; ++j) acc[i][j] = (f32x4){0.f, 0.f, 0.f, 0.f};

    for (int k0 = 0; k0 < K; k0 += 32) {
#pragma unroll
        for (int jj = 0; jj < 2; ++jj) {
            const int slot = w * 2 + jj;              // 0..7
            const int row  = slot * 16 + sr;
            const int g    = sc ^ ((row >> 1) & 3);   // source col-group swizzle
            gld_lds16(&A[(long long)(m0 + row) * lda + k0 + g * 8], &As[slot * 512]);
            gld_lds16(&Bm[(long long)(n0 + row) * ldb + k0 + g * 8], &Bs[slot * 512]);
        }
        __syncthreads();

        U4 af[4], bf[4];
#pragma unroll
        for (int i = 0; i < 4; ++i) {
            const int ra = mw + i * 16 + m;
            af[i].u = *(const uint4*)&As[ra * 32 + (q4 ^ ((ra >> 1) & 3)) * 8];
            const int rb = nw + i * 16 + m;
            bf[i].u = *(const uint4*)&Bs[rb * 32 + (q4 ^ ((rb >> 1) & 3)) * 8];
        }
#pragma unroll
        for (int i = 0; i < 4; ++i)
#pragma unroll
            for (int j = 0; j < 4; ++j)
                acc[i][j] = __builtin_amdgcn_mfma_f32_16x16x32_bf16(
                    af[i].v, bf[j].v, acc[i][j], 0, 0, 0);
        __syncthreads();
    }

#pragma unroll
    for (int j = 0; j < 4; ++j) {
        const int cn = n0 + nw + j * 16 + m;
        const float bv = bias ? bias[cn] : 0.0f;
#pragma unroll
        for (int i = 0; i < 4; ++i) {
            const int rw = m0 + mw + i * 16 + q4 * 4;
#pragma unroll
            for (int r = 0; r < 4; ++r) {
                const float val = acc[i][j][r] * scale + bv;
                if (OUT_BF16)
                    ((ushort*)Cv)[(long long)z * cOff + (long long)(rw + r) * ldc + cn] =
                        (ushort)bfbits(val);
                else
                    ((float*)Cv)[(long long)z * cOff + (long long)(rw + r) * ldc + cn] = val;
            }
        }
    }
}

// ---------------------------------------------------------------------------
// f32 -> bf16 converters
// ---------------------------------------------------------------------------
__global__ __launch_bounds__(256) void conv_bf16(
    const float* __restrict__ s, ushort* __restrict__ d)
{
    const long long i = ((long long)blockIdx.x * 256 + threadIdx.x) * 4;
    float4 v = *(const float4*)&s[i];
    uint2 p; p.x = pack2bf(v.x, v.y); p.y = pack2bf(v.z, v.w);
    *(uint2*)&d[i] = p;
}

// wkv_a_w (576,2048) -> padded (640,2048) bf16, zero rows 576..639
__global__ __launch_bounds__(256) void conv_wkva(
    const float* __restrict__ s, ushort* __restrict__ d)
{
    const int i = (blockIdx.x * 256 + threadIdx.x) * 4;   // < 640*2048
    const int r = i >> 11;
    uint2 p = make_uint2(0u, 0u);
    if (r < 576) {
        float4 v = *(const float4*)&s[i];
        p.x = pack2bf(v.x, v.y); p.y = pack2bf(v.z, v.w);
    }
    *(uint2*)&d[i] = p;
}

// wkv_b nope half: W(16,256,512)[:, :128, :] -> T(16,512,128) bf16 (transposed)
__global__ __launch_bounds__(256) void conv_wkvb_t(
    const float* __restrict__ Wsrc, ushort* __restrict__ T)
{
    __shared__ float tile[32][33];
    const int h = blockIdx.z, dt = blockIdx.y, ct = blockIdx.x;
    const int tx = threadIdx.x & 31, ty = threadIdx.x >> 5;
#pragma unroll
    for (int p8 = 0; p8 < 4; ++p8) {
        const int dd = dt * 32 + ty + p8 * 8;
        tile[ty + p8 * 8][tx] = Wsrc[((long long)(h * 256 + dd)) * 512 + ct * 32 + tx];
    }
    __syncthreads();
#pragma unroll
    for (int p8 = 0; p8 < 4; ++p8) {
        const int cc = ct * 32 + ty + p8 * 8;
        T[((long long)h * 512 + cc) * 128 + dt * 32 + tx] =
            (ushort)bfbits(tile[tx][ty + p8 * 8]);
    }
}

// wkv_b v half: W(16,256,512)[:, 128:, :] -> V(16,128,512) bf16
__global__ __launch_bounds__(256) void conv_wkvbv(
    const float* __restrict__ Wsrc, ushort* __restrict__ V)
{
    const int i = (blockIdx.x * 256 + threadIdx.x) * 4;   // < 16*128*512
    const int h = i >> 16;
    const int rem = i & 65535;
    float4 v = *(const float4*)&Wsrc[((long long)(h * 256 + 128)) * 512 + rem];
    uint2 p; p.x = pack2bf(v.x, v.y); p.y = pack2bf(v.z, v.w);
    *(uint2*)&V[i] = p;
}

// q_raw (bs, h*192+d) f32 -> qn (bs, h*128+d) bf16  (nope cols only)
__global__ __launch_bounds__(256) void conv_qn(
    const float* __restrict__ q_raw, ushort* __restrict__ qn)
{
    const int i = (blockIdx.x * 256 + threadIdx.x) * 4;   // < 4096*2048
    const int bs = i >> 11;
    const int c = i & 2047;
    const int hh = c >> 7, d = c & 127;
    float4 v = *(const float4*)&q_raw[(long long)bs * 3072 + hh * 192 + d];
    uint2 p; p.x = pack2bf(v.x, v.y); p.y = pack2bf(v.z, v.w);
    *(uint2*)&qn[i] = p;
}

// ---------------------------------------------------------------------------
// RoPE on q_raw[...,128:192] -> q_h[...,512:576] bf16, scale folded.
// ---------------------------------------------------------------------------
__global__ __launch_bounds__(256) void rope_q_kernel(
    const float* __restrict__ q_raw, const float* __restrict__ freqs,
    ushort* __restrict__ q_h)
{
    const int idx = blockIdx.x * 256 + threadIdx.x;
    const int i = idx & 31;
    const int h = (idx >> 5) & 15;
    const int s = (idx >> 9) & 2047;
    const int b = idx >> 20;
    const float f = freqs[s * 32 + i];
    float cs, sn;
    __sincosf(f, &sn, &cs);
    const int row = (b * S_ + s) * H_ + h;
    const float a  = q_raw[(long long)row * 192 + 128 + 2 * i];
    const float bb = q_raw[(long long)row * 192 + 128 + 2 * i + 1];
    *(uint*)&q_h[(long long)row * 576 + 512 + 2 * i] =
        pack2bf((a * cs - bb * sn) * SCALE_, (a * sn + bb * cs) * SCALE_);
}

// ---------------------------------------------------------------------------
// kv post: bias add + rmsnorm(kv[:512]) and rope(kv[512:576]) -> kv_h bf16.
// kv_raw has padded row stride 640. One wave per (b,s).
// ---------------------------------------------------------------------------
__global__ __launch_bounds__(64) void kv_post_kernel(
    const float* __restrict__ kv_raw, const float* __restrict__ bias,
    const float* __restrict__ w, const float* __restrict__ freqs,
    ushort* __restrict__ kv_h)
{
    const int bs = blockIdx.x;
    const int lane = threadIdx.x;
    const float* src = kv_raw + (long long)bs * 640;
    ushort* dst = kv_h + (long long)bs * 576;

    const int c = 4 * lane;
    float4 v0 = *(const float4*)&src[c];
    float4 v1 = *(const float4*)&src[256 + c];
    float4 b0 = *(const float4*)&bias[c];
    float4 b1 = *(const float4*)&bias[256 + c];
    v0.x += b0.x; v0.y += b0.y; v0.z += b0.z; v0.w += b0.w;
    v1.x += b1.x; v1.y += b1.y; v1.z += b1.z; v1.w += b1.w;
    float ss = v0.x * v0.x + v0.y * v0.y + v0.z * v0.z + v0.w * v0.w +
               v1.x * v1.x + v1.y * v1.y + v1.z * v1.z + v1.w * v1.w;
#pragma unroll
    for (int o = 32; o; o >>= 1) ss += __shfl_xor(ss, o, 64);
    const float rs = rsqrtf(ss * (1.0f / 512.0f) + EPS_);

    float4 w0 = *(const float4*)&w[c];
    float4 w1 = *(const float4*)&w[256 + c];
    uint2 p0, p1;
    p0.x = pack2bf(v0.x * rs * w0.x, v0.y * rs * w0.y);
    p0.y = pack2bf(v0.z * rs * w0.z, v0.w * rs * w0.w);
    p1.x = pack2bf(v1.x * rs * w1.x, v1.y * rs * w1.y);
    p1.y = pack2bf(v1.z * rs * w1.z, v1.w * rs * w1.w);
    *(uint2*)&dst[c] = p0;
    *(uint2*)&dst[256 + c] = p1;

    if (lane < 32) {
        const int s = bs & 2047;
        const float f = freqs[s * 32 + lane];
        float cs, sn;
        __sincosf(f, &sn, &cs);
        const float a  = src[512 + 2 * lane]     + bias[512 + 2 * lane];
        const float b2 = src[512 + 2 * lane + 1] + bias[512 + 2 * lane + 1];
        *(uint*)&dst[512 + 2 * lane] = pack2bf(a * cs - b2 * sn, a * sn + b2 * cs);
    }
}

// ---------------------------------------------------------------------------
// MFMA flash attention v4 (latent space, causal), head-amortized KV.
// Block = 16 q rows x 4 heads (one head per wave) of one (b, q-group).
// KV tile = 32 t, staged ONCE per block:
//   - K tile row-major in LDS via async global_load_lds (pad 584 halves)
//   - V^T packed t-pair dwords, stride 21 (writes & reads ~2-way = free)
// Per wave per tile: S^T = K.Q^T (36 MFMA, full 576 k), online softmax in
// C-layout (lane-local m,l per q-col), P^T -> B-frag via 8 shuffles,
// PV over full 512 d (32 MFMA). O = 32 f32x4. 2 barriers/tile.
// LDS 80384 B -> 2 blocks/CU; VGPR ~230 -> 2 waves/SIMD.
// ---------------------------------------------------------------------------
__global__ __launch_bounds__(256, 2) void attn_kernel(
    const ushort* __restrict__ q_h,   // (B,S,H,576), q*scale
    const ushort* __restrict__ kv_h,  // (B,S,576)
    ushort* __restrict__ o_h)         // (B,S,H,512)
{
    __shared__ ushort kvs[32 * 584];   // K tile, 37376 B (73 uint4/row, last=pad)
    __shared__ uint   vts[512 * 21];   // V^T tile, 43008 B

    const int qs   = 127 - (int)blockIdx.x;   // big blocks first
    const int hg   = blockIdx.y;
    const int b    = blockIdx.z;
    const int tid  = threadIdx.x;
    const int wid  = tid >> 6;
    const int lane = tid & 63;
    const int m    = lane & 15;
    const int q4   = lane >> 4;
    const int h    = hg * 4 + wid;            // one head per wave
    const int row0 = qs * 16;
    const int sRow = row0 + m;

    // Q fragments (full 576 k): lane holds Q[sRow][k = 32f + 8*q4 + j]
    U4 qf[18];
    {
        const uint4* qp = (const uint4*)(q_h + ((long long)(b * S_ + sRow) * H_ + h) * 576);
#pragma unroll
        for (int f = 0; f < 18; ++f) qf[f].u = qp[f * 4 + q4];
    }

    f32x4 o[32];
#pragma unroll
    for (int c = 0; c < 32; ++c) o[c] = (f32x4){0.f, 0.f, 0.f, 0.f};
    float mrun = -3.0e38f, lrun = 0.0f;

    const ushort* kvb = kv_h + (long long)b * S_ * 576;
    const int nT = (row0 + 47) >> 5;          // tiles covering t <= row0+15

    for (int it = 0; it < nT; ++it) {
        const int t0 = it * 32;
        __syncthreads();   // prev tile's LDS reads done

        // ---- stage K tile via async global_load_lds (2336 uint4 slots)
#pragma unroll
        for (int j = 0; j < 10; ++j) {
            const int slot = tid + j * 256;
            if (slot < 2336) {
                const int t = slot / 73;
                const int c = slot - t * 73;
                const ushort* src = &kvb[(t0 + t) * 576 + (c < 72 ? c * 8 : 0)];
                gld_lds16(src, &kvs[(slot & ~63) * 8]);
            }
        }

        // ---- build V^T (overlaps the async K stage; global source, L2-hot)
#pragma unroll
        for (int jj = 0; jj < 4; ++jj) {
            const int idx = tid + jj * 256;
            const int tp = idx & 15;
            const int dg = idx >> 4;          // 0..63, 8 d-rows each
            const uint4 a = *(const uint4*)&kvb[(t0 + 2 * tp) * 576 + dg * 8];
            const uint4 c = *(const uint4*)&kvb[(t0 + 2 * tp + 1) * 576 + dg * 8];
            uint* vp = &vts[(dg * 8) * 21 + tp];
            vp[0 * 21] = (a.x & 0xffffu) | (c.x << 16);
            vp[1 * 21] = (a.x >> 16)     | (c.x & 0xffff0000u);
            vp[2 * 21] = (a.y & 0xffffu) | (c.y << 16);
            vp[3 * 21] = (a.y >> 16)     | (c.y & 0xffff0000u);
            vp[4 * 21] = (a.z & 0xffffu) | (c.z << 16);
            vp[5 * 21] = (a.z >> 16)     | (c.z & 0xffff0000u);
            vp[6 * 21] = (a.w & 0xffffu) | (c.w << 16);
            vp[7 * 21] = (a.w >> 16)     | (c.w & 0xffff0000u);
        }
        __syncthreads();   // K + V^T staged

        // ---- S^T = K . Q^T  (subtile s=1 skipped when fully masked)
        const bool skip1 = (t0 >= row0);
        f32x4 st[2];
        st[1] = (f32x4){0.f, 0.f, 0.f, 0.f};
        {
            f32x4 a2 = (f32x4){0.f, 0.f, 0.f, 0.f};
#pragma unroll
            for (int f = 0; f < 18; ++f) {
                U4 a; a.u = ((const uint4*)kvs)[m * 73 + f * 4 + q4];
                a2 = __builtin_amdgcn_mfma_f32_16x16x32_bf16(a.v, qf[f].v, a2, 0, 0, 0);
            }
            st[0] = a2;
        }
        if (!skip1) {
            f32x4 a2 = (f32x4){0.f, 0.f, 0.f, 0.f};
#pragma unroll
            for (int f = 0; f < 18; ++f) {
                U4 a; a.u = ((const uint4*)kvs)[(16 + m) * 73 + f * 4 + q4];
                a2 = __builtin_amdgcn_mfma_f32_16x16x32_bf16(a.v, qf[f].v, a2, 0, 0, 0);
            }
            st[1] = a2;
        }

        // ---- mask + online softmax (q-col = m, lane-local state)
        float p[2][4];
        float vmax = -3.0e38f;
#pragma unroll
        for (int s = 0; s < 2; ++s)
#pragma unroll
            for (int r = 0; r < 4; ++r) {
                const int t = t0 + s * 16 + q4 * 4 + r;
                const float v = (t <= sRow) ? st[s][r] : -3.0e38f;
                p[s][r] = v;
                vmax = fmaxf(vmax, v);
            }
        vmax = fmaxf(vmax, __shfl_xor(vmax, 16, 64));
        vmax = fmaxf(vmax, __shfl_xor(vmax, 32, 64));
        const float mnew = fmaxf(mrun, vmax);
        const float alpha = __expf(mrun - mnew);
        float tsum = 0.f;
#pragma unroll
        for (int s = 0; s < 2; ++s)
#pragma unroll
            for (int r = 0; r < 4; ++r) {
                p[s][r] = __expf(p[s][r] - mnew);
                tsum += p[s][r];
            }
        tsum += __shfl_xor(tsum, 16, 64);
        tsum += __shfl_xor(tsum, 32, 64);
        mrun = mnew;
        lrun = lrun * alpha + tsum;

        // ---- P^T -> PV B-fragment (k = 8*q4+j over t) via 8 shuffles
        U4 bb;
        {
            uint pk00 = pack2bf(p[0][0], p[0][1]);
            uint pk01 = pack2bf(p[0][2], p[0][3]);
            uint pk10 = pack2bf(p[1][0], p[1][1]);
            uint pk11 = pack2bf(p[1][2], p[1][3]);
            const int srcA = ((lane >> 4) & 1) * 32 + m;
            const int srcB = srcA + 16;
            uint a00 = (uint)__shfl((int)pk00, srcA, 64);
            uint a01 = (uint)__shfl((int)pk01, srcA, 64);
            uint a10 = (uint)__shfl((int)pk10, srcA, 64);
            uint a11 = (uint)__shfl((int)pk11, srcA, 64);
            uint b00 = (uint)__shfl((int)pk00, srcB, 64);
            uint b01 = (uint)__shfl((int)pk01, srcB, 64);
            uint b10 = (uint)__shfl((int)pk10, srcB, 64);
            uint b11 = (uint)__shfl((int)pk11, srcB, 64);
            const bool hi2 = (lane >> 5) & 1;
            bb.u.x = hi2 ? a10 : a00;
            bb.u.y = hi2 ? a11 : a01;
            bb.u.z = hi2 ? b10 : b00;
            bb.u.w = hi2 ? b11 : b01;
        }

        // ---- PV over full 512 d (O^T = V^T . P^T)
#pragma unroll
        for (int c = 0; c < 32; ++c) {
            const int d = c * 16 + m;
            U4 av; av.u = *(const uint4*)&vts[d * 21 + q4 * 4];
            o[c].x *= alpha; o[c].y *= alpha; o[c].z *= alpha; o[c].w *= alpha;
            o[c] = __builtin_amdgcn_mfma_f32_16x16x32_bf16(av.v, bb.v, o[c], 0, 0, 0);
        }
    }

    // ---- epilogue: lane holds O^T[d = 16c + 4*q4 + r][q = m]
    const float inv = 1.0f / lrun;
    ushort* op = o_h + ((long long)(b * S_ + sRow) * H_ + h) * 512;
#pragma unroll
    for (int c = 0; c < 32; ++c) {
        uint2 pv;
        pv.x = pack2bf(o[c].x * inv, o[c].y * inv);
        pv.y = pack2bf(o[c].z * inv, o[c].w * inv);
        *(uint2*)&op[c * 16 + q4 * 4] = pv;
    }
}

// ---------------------------------------------------------------------------
extern "C" void kernel_launch(void* const* d_in, const int* in_sizes, int n_in,
                              void* d_out, int out_size, void* d_ws, size_t ws_size,
                              hipStream_t stream)
{
    const float* x         = (const float*)d_in[0];
    const float* freqs     = (const float*)d_in[1];
    // d_in[2] = mask (unused: causal handled analytically)
    const float* wq_w      = (const float*)d_in[3];
    const float* wq_b      = (const float*)d_in[4];
    const float* wkv_a_w   = (const float*)d_in[5];
    const float* wkv_a_b   = (const float*)d_in[6];
    const float* kv_norm_w = (const float*)d_in[7];
    const float* wkv_b_w   = (const float*)d_in[8];
    const float* wo_w      = (const float*)d_in[9];
    const float* wo_b      = (const float*)d_in[10];
    float* out = (float*)d_out;

    // ---- workspace layout (202.4 MB)
    char* w = (char*)d_ws;
    ushort* x_bf    = (ushort*)w;  w += 16777216;   // (4096,2048) bf16
    ushort* wq_bf   = (ushort*)w;  w += 12582912;   // (3072,2048) bf16
    ushort* wkva_bf = (ushort*)w;  w += 2621440;    // (640,2048)  bf16 padded
    ushort* wo_bf   = (ushort*)w;  w += 8388608;    // (2048,2048) bf16
    ushort* wkvbT   = (ushort*)w;  w += 2097152;    // (16,512,128) bf16
    ushort* wkvbV   = (ushort*)w;  w += 2097152;    // (16,128,512) bf16
    float*  kv_raw  = (float*)w;   w += 10485760;   // (4096,640)  f32
    ushort* kv_h    = (ushort*)w;  w += 4718592;    // (4096,576)  bf16
    char* RA = w;                  w += 67108864;
    float*  q_raw = (float*)RA;                     // (4096,3072) f32
    ushort* qn_bf = (ushort*)(RA + 50331648);       // (4096,2048) bf16
    ushort* o_h   = (ushort*)RA;                    // (4096,8192) bf16 (q dead)
    char* RB = w;                  w += 75497472;
    ushort* q_h  = (ushort*)RB;                     // (4096,9216) bf16
    ushort* outv = (ushort*)RB;                     // (4096,2048) bf16 (q_h dead)

    dim3 blk(256);

    // ---- bf16 conversions
    conv_bf16 <<<dim3(8192), blk, 0, stream>>>(x, x_bf);         // 8.39M
    conv_bf16 <<<dim3(6144), blk, 0, stream>>>(wq_w, wq_bf);     // 6.29M
    conv_wkva <<<dim3(1280), blk, 0, stream>>>(wkv_a_w, wkva_bf);
    conv_bf16 <<<dim3(4096), blk, 0, stream>>>(wo_w, wo_bf);     // 4.19M
    conv_wkvb_t<<<dim3(16, 4, 16), blk, 0, stream>>>(wkv_b_w, wkvbT);
    conv_wkvbv <<<dim3(1024), blk, 0, stream>>>(wkv_b_w, wkvbV);

    // 1) q_raw = x @ wq_w^T + wq_b   (M=4096, N=3072, K=2048)
    mgemm<false><<<dim3(24, 32, 1), blk, 0, stream>>>(
        x_bf, 2048, 0LL, wq_bf, 2048, 0LL, wq_b, 1.0f, q_raw, 3072, 0LL, 2048);

    // 2) kv_raw = x @ wkv_a_w^T   (N=640 padded; bias folded into kv_post)
    mgemm<false><<<dim3(5, 32, 1), blk, 0, stream>>>(
        x_bf, 2048, 0LL, wkva_bf, 2048, 0LL, nullptr, 1.0f, kv_raw, 640, 0LL, 2048);

    // 3) RoPE(q_pe) -> q_h[...,512:576], scale folded
    rope_q_kernel<<<dim3(8192), blk, 0, stream>>>(q_raw, freqs, q_h);
    // 3b) q_nope -> packed bf16
    conv_qn<<<dim3(8192), blk, 0, stream>>>(q_raw, qn_bf);

    // 4) bias + rmsnorm + rope -> kv_h
    kv_post_kernel<<<dim3(4096), dim3(64), 0, stream>>>(
        kv_raw, wkv_a_b, kv_norm_w, freqs, kv_h);

    // 5) q_h[...,0:512] = (q_nope @ wkv_b[h,:128,:]) * scale  (M=4096,N=512,K=128 x16)
    mgemm<true><<<dim3(4, 32, 16), blk, 0, stream>>>(
        qn_bf, 2048, 128LL, wkvbT, 128, 65536LL, nullptr, SCALE_,
        q_h, 9216, 576LL, 128);

    // 6) MFMA flash attention v4 -> o_h
    attn_kernel<<<dim3(128, 4, 2), blk, 0, stream>>>(q_h, kv_h, o_h);

    // 7) outv = attn @ wkv_b[h,128:,:]^T  (M=4096,N=128,K=512 x16)
    mgemm<true><<<dim3(1, 32, 16), blk, 0, stream>>>(
        o_h, 8192, 512LL, wkvbV, 512, 65536LL, nullptr, 1.0f,
        outv, 2048, 128LL, 512);

    // 8) out = outv @ wo_w^T + wo_b   (M=4096, N=2048, K=2048)
    mgemm<false><<<dim3(16, 32, 1), blk, 0, stream>>>(
        outv, 2048, 0LL, wo_bf, 2048, 0LL, wo_b, 1.0f, out, 2048, 0LL, 2048);
}